// Round 3
// baseline (246.258 us; speedup 1.0000x reference)
//
#include <hip/hip_runtime.h>
#include <math.h>

// Chamfer k-NN (k=16, L2), R16: binned window scan with TRUE union-tau.
// R15 post-mortem: tau = min of per-lane 16ths ~= union-100th -> stop radius
// ~1.9x true r16 -> ~2x steps, loose enqueue gate -> many collective drains;
// 28k VALU-inst/wave measured vs 20k for brute force. Fixes:
//  - GROUP=4 lanes/query (was 8): halves list redundancy.
//  - union-tau: at each drain, merge a COPY of the quad's sorted lists
//    (2 shfl_xor halver rounds) -> tau = exact current union-16th (still an
//    upper bound on the final 16th -> pruning exact). Radius 1.9x -> 1.0x,
//    and the first drain (96 x-closest candidates) gives near-final tau.
//  - 64-thread blocks (1 wave): no syncthreads, 8KB LDS queue, per-block
//    imbalance limited to its own 16 x-coherent queries.
//  - epilogue: 2 halver rounds, final bitonic dropped (sum is order-free).
// Pipeline: init -> pack (pred4/tgt4 + x-min/max) -> binsort (NB=512
// counting sort) -> scan (two-sided outward, stop at dx >= sqrt(tau_d2)+w).

#define INFV    3.0e38f
#define QDEPTH  32
#define NB      512

__device__ __forceinline__ void ce(float& a, float& b) {
    float lo = fminf(a, b);
    b = fmaxf(a, b);
    a = lo;
}

// bitonic merge-sort of a bitonic 16-seq (stages 8,4,2,1 = 32 CE), ascending
__device__ __forceinline__ void bitonic16(float (&s)[16]) {
    ce(s[0],s[8]);  ce(s[1],s[9]);  ce(s[2],s[10]); ce(s[3],s[11]);
    ce(s[4],s[12]); ce(s[5],s[13]); ce(s[6],s[14]); ce(s[7],s[15]);
    ce(s[0],s[4]);  ce(s[1],s[5]);  ce(s[2],s[6]);  ce(s[3],s[7]);
    ce(s[8],s[12]); ce(s[9],s[13]); ce(s[10],s[14]);ce(s[11],s[15]);
    ce(s[0],s[2]);  ce(s[1],s[3]);  ce(s[4],s[6]);  ce(s[5],s[7]);
    ce(s[8],s[10]); ce(s[9],s[11]); ce(s[12],s[14]);ce(s[13],s[15]);
    ce(s[0],s[1]);  ce(s[2],s[3]);  ce(s[4],s[5]);  ce(s[6],s[7]);
    ce(s[8],s[9]);  ce(s[10],s[11]);ce(s[12],s[13]);ce(s[14],s[15]);
}

// Merge up to 8 queued values (qb[(base+i)*64], i<cnt-base) into sorted s[16].
__device__ __forceinline__ void drain_batch(float (&s)[16], const float* qb,
                                            int base, int cnt)
{
    float q[8];
#pragma unroll
    for (int i = 0; i < 8; ++i) {
        float v = qb[(base + i) * 64];
        q[i] = (base + i < cnt) ? v : INFV;
    }
    // sort8 ascending -- Batcher odd-even, 19 CE
    ce(q[0],q[1]); ce(q[2],q[3]); ce(q[4],q[5]); ce(q[6],q[7]);
    ce(q[0],q[2]); ce(q[1],q[3]); ce(q[4],q[6]); ce(q[5],q[7]);
    ce(q[1],q[2]); ce(q[5],q[6]);
    ce(q[0],q[4]); ce(q[1],q[5]); ce(q[2],q[6]); ce(q[3],q[7]);
    ce(q[2],q[4]); ce(q[3],q[5]);
    ce(q[1],q[2]); ce(q[3],q[4]); ce(q[5],q[6]);
    // bitonic halver vs sorted s[16]
#pragma unroll
    for (int i = 0; i < 8; ++i) s[8 + i] = fminf(s[8 + i], q[7 - i]);
    bitonic16(s);
}

// order-preserving float<->uint map for atomicMin/Max
__device__ __forceinline__ unsigned fmap(float f) {
    unsigned u = __float_as_uint(f);
    return (u & 0x80000000u) ? ~u : (u | 0x80000000u);
}
__device__ __forceinline__ float funmap(unsigned u) {
    unsigned v = (u & 0x80000000u) ? (u & 0x7fffffffu) : ~u;
    return __uint_as_float(v);
}

__global__ void init_kernel(float* __restrict__ out, unsigned* __restrict__ mm) {
    if (threadIdx.x == 0) {
        out[0] = 0.0f;          // replaces memset (poisoned 0xAA)
        mm[0] = 0xFFFFFFFFu;    // min sentinel (mapped order)
        mm[1] = 0u;             // max sentinel
    }
}

__global__ __launch_bounds__(256) void pack_kernel(
    const float* __restrict__ src, const float* __restrict__ tgt,
    const float* __restrict__ flow,
    float4* __restrict__ pred4, float4* __restrict__ tgt4,
    unsigned* __restrict__ mm, int BN, int BM)
{
    int i = blockIdx.x * 256 + threadIdx.x;
    float lmin = INFV, lmax = -INFV;
    if (i < BN) {
        float x = src[3 * i + 0] + flow[3 * i + 0];
        float y = src[3 * i + 1] + flow[3 * i + 1];
        float z = src[3 * i + 2] + flow[3 * i + 2];
        pred4[i] = make_float4(x, y, z, fmaf(x, x, fmaf(y, y, z * z)));
        lmin = fminf(lmin, x); lmax = fmaxf(lmax, x);
    }
    if (i < BM) {
        float x = tgt[3 * i + 0];
        float y = tgt[3 * i + 1];
        float z = tgt[3 * i + 2];
        tgt4[i] = make_float4(x, y, z, fmaf(x, x, fmaf(y, y, z * z)));
        lmin = fminf(lmin, x); lmax = fmaxf(lmax, x);
    }
#pragma unroll
    for (int off = 32; off > 0; off >>= 1) {
        lmin = fminf(lmin, __shfl_down(lmin, off));
        lmax = fmaxf(lmax, __shfl_down(lmax, off));
    }
    if ((threadIdx.x & 63) == 0) {
        atomicMin(mm + 0, fmap(lmin));
        atomicMax(mm + 1, fmap(lmax));
    }
}

__device__ __forceinline__ int binof(float x, float xmin, float sc) {
    int bn = (int)((x - xmin) * sc);
    return bn < 0 ? 0 : (bn > NB - 1 ? NB - 1 : bn);
}

// counting-sort one point set into x-bins. blockIdx.x: 0=pred b0, 1=pred b1,
// 2=tgt b0, 3=tgt b1. Order within a bin is arbitrary.
__global__ __launch_bounds__(1024) void binsort_kernel(
    const float4* __restrict__ pred4, const float4* __restrict__ tgt4,
    float4* __restrict__ ps4, float4* __restrict__ ts4,
    int* __restrict__ goffs, const unsigned* __restrict__ mm, int N, int M)
{
    const int a = blockIdx.x, tid = threadIdx.x;
    const int n = (a < 2) ? N : M;
    const float4* src = (a < 2) ? pred4 + (size_t)a * N : tgt4 + (size_t)(a - 2) * M;
    float4* dst       = (a < 2) ? ps4   + (size_t)a * N : ts4  + (size_t)(a - 2) * M;

    __shared__ int hist[NB];
    __shared__ int offs[NB + 1];
    __shared__ int cur[NB];
    const float xmin = funmap(mm[0]);
    const float xmax = funmap(mm[1]);
    const float range = xmax - xmin;
    const float sc = (range > 0.f) ? (float)NB / range : 0.f;

    if (tid < NB) { hist[tid] = 0; cur[tid] = 0; }
    __syncthreads();
    for (int i = tid; i < n; i += 1024)
        atomicAdd(&hist[binof(src[i].x, xmin, sc)], 1);
    __syncthreads();
    for (int off = 1; off < NB; off <<= 1) {
        int t = 0;
        if (tid < NB && tid >= off) t = hist[tid - off];
        __syncthreads();
        if (tid < NB) hist[tid] += t;
        __syncthreads();
    }
    if (tid < NB) offs[tid + 1] = hist[tid];
    if (tid == 0) offs[0] = 0;
    __syncthreads();
    for (int i = tid; i < n; i += 1024) {
        float4 v = src[i];
        int bn = binof(v.x, xmin, sc);
        int slot = atomicAdd(&cur[bn], 1);
        dst[offs[bn] + slot] = v;
    }
    if (tid <= NB) goffs[a * (NB + 1) + tid] = offs[tid];
}

// one wave per block; 16 queries/wave, 4 lanes/query (stride 4)
__global__ __launch_bounds__(64, 2) void scan_kernel(
    const float4* __restrict__ ps4, const float4* __restrict__ ts4,
    const int* __restrict__ goffs, const unsigned* __restrict__ mm,
    float* __restrict__ out, int N, int M, float scale_out)
{
    __shared__ float qbuf[QDEPTH * 64];    // 8 KB per-thread queues, stride 64

    const int tid = threadIdx.x;
    const int z = blockIdx.y, b = z >> 1, dir = z & 1;
    const int nq   = dir ? M : N;
    const int nref = dir ? N : M;
    const float4* Q = dir ? (ts4 + (size_t)b * M) : (ps4 + (size_t)b * N);
    const float4* R = dir ? (ps4 + (size_t)b * N) : (ts4 + (size_t)b * M);
    const int oid   = dir ? b : 2 + b;     // offsets id of the REF array

    // block-chunk remap: mix dense/sparse x-regions across CUs
    const int W = gridDim.x;
    const int c = ((W & (W - 1)) == 0) ? ((blockIdx.x * 45) & (W - 1))
                                       : blockIdx.x;
    const int qidx = c * 16 + (tid >> 2);  // 16 consecutive bin-sorted queries
    const bool qv = qidx < nq;
    const int l = tid & 3;                 // lane within quad

    float4 q = qv ? Q[qidx] : make_float4(0.f, 0.f, 0.f, 0.f);
    const float qx = q.x, q2 = q.w;
    const float nx = -2.f * q.x, ny = -2.f * q.y, nz = -2.f * q.z;

    const float xmin = funmap(mm[0]);
    const float range = funmap(mm[1]) - xmin;
    const float w = range * (1.0f / NB);
    const float sc = (range > 0.f) ? (float)NB / range : 0.f;
    const int start = goffs[oid * (NB + 1) + binof(qx, xmin, sc)];

    float s[16];
#pragma unroll
    for (int i = 0; i < 16; ++i) s[i] = INFV;
    float tau     = qv ? INFV : -INFV;     // invalid quads never enqueue
    float rtau_pw = qv ? INFV : -INFV;     // and stop after one group
    int   cnt = 0, lim = 17;               // early first drain -> near-final tau
    const float* qb_tid = qbuf + tid;

    // s[] is c-space (c = d2 - q2); tau (c-space, shared within quad) gates
    // enqueues; stop radius converts to true d2: sqrt(max(tau+q2,0)) + w.
    // tau = EXACT current union-16th of the quad: merge a COPY of the 4
    // sorted lists (halver rounds) -- s itself stays disjoint per lane.
#define DRAIN_ALL() do {                                            \
        drain_batch(s, qb_tid, 0, cnt);                             \
        if (__ballot(cnt >  8)) drain_batch(s, qb_tid,  8, cnt);    \
        if (__ballot(cnt > 16)) drain_batch(s, qb_tid, 16, cnt);    \
        if (__ballot(cnt > 24)) drain_batch(s, qb_tid, 24, cnt);    \
        cnt = 0;                                                    \
        float t[16], u[16];                                         \
        _Pragma("unroll")                                           \
        for (int i = 0; i < 16; ++i) t[i] = s[i];                   \
        _Pragma("unroll")                                           \
        for (int i = 0; i < 16; ++i) u[i] = __shfl_xor(t[i], 1);    \
        _Pragma("unroll")                                           \
        for (int i = 0; i < 16; ++i) t[i] = fminf(t[i], u[15 - i]); \
        bitonic16(t);                                               \
        _Pragma("unroll")                                           \
        for (int i = 0; i < 16; ++i) u[i] = __shfl_xor(t[i], 2);    \
        _Pragma("unroll")                                           \
        for (int i = 0; i < 16; ++i) t[i] = fminf(t[i], u[15 - i]); \
        float mx = t[0];                                            \
        _Pragma("unroll")                                           \
        for (int i = 1; i < 16; ++i) mx = fmaxf(mx, t[i]);          \
        if (qv) { tau = mx;                                         \
                  rtau_pw = sqrtf(fmaxf(mx + q2, 0.0f)) + w; }      \
    } while (0)

    // 8 candidates per lane per group (stride 4); loads hoisted ahead of the
    // act-chain. Unconditional slot write + predicated count advance.
#define PROC8(DIRSGN) do {                                          \
        float4 rr[8];                                               \
        const int pLast = p + (DIRSGN) * 28;                        \
        if (((unsigned)p < (unsigned)nref) &&                       \
            ((unsigned)pLast < (unsigned)nref)) {                   \
            _Pragma("unroll")                                       \
            for (int u = 0; u < 8; ++u)                             \
                rr[u] = R[p + (DIRSGN) * (u * 4)];                  \
        } else {                                                    \
            _Pragma("unroll")                                       \
            for (int u = 0; u < 8; ++u) {                           \
                int pi = p + (DIRSGN) * (u * 4);                    \
                rr[u] = R[((unsigned)pi < (unsigned)nref) ? pi : 0];\
            }                                                       \
        }                                                           \
        _Pragma("unroll")                                           \
        for (int u = 0; u < 8; ++u) {                               \
            const int pi = p + (DIRSGN) * (u * 4);                  \
            const bool inb = (unsigned)pi < (unsigned)nref;         \
            const float dxs = ((DIRSGN) > 0) ? (rr[u].x - qx)       \
                                             : (qx - rr[u].x);      \
            const bool go = act & inb & (dxs < rtau_pw);            \
            const float cd = fmaf(nx, rr[u].x, fmaf(ny, rr[u].y,    \
                             fmaf(nz, rr[u].z, rr[u].w)));          \
            qbuf[cnt * 64 + tid] = cd;                              \
            cnt += (go & (cd < tau)) ? 1 : 0;                       \
            act = go;                                               \
        }                                                           \
        p += (DIRSGN) * 32;                                         \
    } while (0)

    // right phase: positions start+l, +4 ...
    {
        int p = start + l;
        bool act = true;
        while (__ballot(act)) {
            PROC8(1);
            if (__ballot(cnt >= lim)) { DRAIN_ALL(); lim = QDEPTH - 7; }
        }
    }
    // left phase: positions start-4+l, -4 ... (covers everything < start)
    {
        int p = start - 4 + l;
        bool act = true;
        while (__ballot(act)) {
            PROC8(-1);
            if (__ballot(cnt >= lim)) { DRAIN_ALL(); lim = QDEPTH - 7; }
        }
    }
    if (__ballot(cnt > 0)) DRAIN_ALL();

#undef PROC8
#undef DRAIN_ALL

    // quad merge (destructive, lists disjoint): halver+sort, halver; the
    // final set is bitonic -- summing sqrt needs no final sort.
    {
        float u[16];
#pragma unroll
        for (int i = 0; i < 16; ++i) u[i] = __shfl_xor(s[i], 1);
#pragma unroll
        for (int i = 0; i < 16; ++i) s[i] = fminf(s[i], u[15 - i]);
        bitonic16(s);
#pragma unroll
        for (int i = 0; i < 16; ++i) u[i] = __shfl_xor(s[i], 2);
#pragma unroll
        for (int i = 0; i < 16; ++i) s[i] = fminf(s[i], u[15 - i]);
    }

    float acc = 0.0f;
    if (qv) {
#pragma unroll
        for (int i = 0; i < 16; ++i)
            acc += sqrtf(fmaxf(s[i] + q2, 0.0f));   // true d2 = c + |q|^2
    }
#pragma unroll
    for (int off = 32; off > 0; off >>= 1) acc += __shfl_down(acc, off);
    if (tid == 0) atomicAdd(out, acc * scale_out);  // each query counted 4x
}

extern "C" void kernel_launch(void* const* d_in, const int* in_sizes, int n_in,
                              void* d_out, int out_size, void* d_ws, size_t ws_size,
                              hipStream_t stream) {
    const float* src  = (const float*)d_in[0];   // pc_source [B,N,3]
    const float* tgt  = (const float*)d_in[1];   // pc_target [B,M,3]
    const float* flow = (const float*)d_in[2];   // pred_flow [B,N,3]
    float* out = (float*)d_out;

    const int B = 2;                              // per reference setup
    const int N = in_sizes[0] / (B * 3);
    const int M = in_sizes[1] / (B * 3);
    const int BN = B * N, BM = B * M;

    // workspace: pred4 | tgt4 | ps4 (bin-sorted pred) | ts4 | goffs | minmax
    float4* pred4 = (float4*)d_ws;
    float4* tgt4  = pred4 + BN;
    float4* ps4   = tgt4 + BM;
    float4* ts4   = ps4 + BN;
    int*    goffs = (int*)(ts4 + BM);             // 4*(NB+1) ints
    unsigned* mm  = (unsigned*)(goffs + 4 * (NB + 1));

    init_kernel<<<1, 64, 0, stream>>>(out, mm);

    int maxBP = (BN > BM) ? BN : BM;
    pack_kernel<<<(maxBP + 255) / 256, 256, 0, stream>>>(
        src, tgt, flow, pred4, tgt4, mm, BN, BM);

    binsort_kernel<<<4, 1024, 0, stream>>>(pred4, tgt4, ps4, ts4, goffs, mm, N, M);

    int maxq = (N > M) ? N : M;
    dim3 grid((maxq + 15) / 16, 2 * B);
    float scale_out = 1.0f / (4.0f * 16.0f * (float)B * (float)N);
    scan_kernel<<<grid, 64, 0, stream>>>(ps4, ts4, goffs, mm, out, N, M, scale_out);
}

// Round 4
// 184.420 us; speedup vs baseline: 1.3353x; 1.3353x over previous
//
#include <hip/hip_runtime.h>
#include <math.h>

// Chamfer k-NN (k=16, L2), R17: tight union-tau + restored occupancy.
// R16 post-mortem: union-tau cut VALU work to brute-force level (69 vs 93
// us-VALU) but GROUP=4 -> 2048 waves = 8/CU -> 11% occupancy -> latency-bound
// (VALUBusy 38%), duration ROSE to 183us. Fix: keep exact tau, restore waves.
//  - GROUP=8 lanes/query, 256-thr blocks: 4096 waves = 16/CU, 4 blocks/CU
//    co-resident (16KB LDS each).
//  - forced drain after first 64-cand group -> near-final tau immediately;
//    QDEPTH 16, drain threshold 9 (enqueues/lane ~2-4 after tau converges).
//  - 128-slot +-1e30 guard pads on sorted ref arrays: no per-candidate
//    bounds check, single-path loads; act-chain dies naturally in guard
//    (>=128 guards provably prevent OOB before the ballot exit).
//  - exact union-tau: 3 shfl_xor halver rounds on a COPY of the octet's
//    sorted lists at each drain (upper bound on final 16th -> exact pruning).
// Pipeline: init -> pack (pred4/tgt4 + x-min/max) -> binsort (NB=512
// counting sort + guards) -> scan (two-sided, stop dx >= sqrt(tau_d2)+w).

#define INFV    3.0e38f
#define QDEPTH  16
#define NB      512
#define GUARD   128

__device__ __forceinline__ void ce(float& a, float& b) {
    float lo = fminf(a, b);
    b = fmaxf(a, b);
    a = lo;
}

// bitonic merge-sort of a bitonic 16-seq (stages 8,4,2,1 = 32 CE), ascending
__device__ __forceinline__ void bitonic16(float (&s)[16]) {
    ce(s[0],s[8]);  ce(s[1],s[9]);  ce(s[2],s[10]); ce(s[3],s[11]);
    ce(s[4],s[12]); ce(s[5],s[13]); ce(s[6],s[14]); ce(s[7],s[15]);
    ce(s[0],s[4]);  ce(s[1],s[5]);  ce(s[2],s[6]);  ce(s[3],s[7]);
    ce(s[8],s[12]); ce(s[9],s[13]); ce(s[10],s[14]);ce(s[11],s[15]);
    ce(s[0],s[2]);  ce(s[1],s[3]);  ce(s[4],s[6]);  ce(s[5],s[7]);
    ce(s[8],s[10]); ce(s[9],s[11]); ce(s[12],s[14]);ce(s[13],s[15]);
    ce(s[0],s[1]);  ce(s[2],s[3]);  ce(s[4],s[5]);  ce(s[6],s[7]);
    ce(s[8],s[9]);  ce(s[10],s[11]);ce(s[12],s[13]);ce(s[14],s[15]);
}

// Merge up to 8 queued values (qb[(base+i)*256], i<cnt-base) into sorted s[16].
__device__ __forceinline__ void drain_batch(float (&s)[16], const float* qb,
                                            int base, int cnt)
{
    float q[8];
#pragma unroll
    for (int i = 0; i < 8; ++i) {
        float v = qb[(base + i) * 256];
        q[i] = (base + i < cnt) ? v : INFV;
    }
    // sort8 ascending -- Batcher odd-even, 19 CE
    ce(q[0],q[1]); ce(q[2],q[3]); ce(q[4],q[5]); ce(q[6],q[7]);
    ce(q[0],q[2]); ce(q[1],q[3]); ce(q[4],q[6]); ce(q[5],q[7]);
    ce(q[1],q[2]); ce(q[5],q[6]);
    ce(q[0],q[4]); ce(q[1],q[5]); ce(q[2],q[6]); ce(q[3],q[7]);
    ce(q[2],q[4]); ce(q[3],q[5]);
    ce(q[1],q[2]); ce(q[3],q[4]); ce(q[5],q[6]);
    // bitonic halver vs sorted s[16]
#pragma unroll
    for (int i = 0; i < 8; ++i) s[8 + i] = fminf(s[8 + i], q[7 - i]);
    bitonic16(s);
}

// order-preserving float<->uint map for atomicMin/Max
__device__ __forceinline__ unsigned fmap(float f) {
    unsigned u = __float_as_uint(f);
    return (u & 0x80000000u) ? ~u : (u | 0x80000000u);
}
__device__ __forceinline__ float funmap(unsigned u) {
    unsigned v = (u & 0x80000000u) ? (u & 0x7fffffffu) : ~u;
    return __uint_as_float(v);
}

__global__ void init_kernel(float* __restrict__ out, unsigned* __restrict__ mm) {
    if (threadIdx.x == 0) {
        out[0] = 0.0f;          // replaces memset (poisoned 0xAA)
        mm[0] = 0xFFFFFFFFu;    // min sentinel (mapped order)
        mm[1] = 0u;             // max sentinel
    }
}

__global__ __launch_bounds__(256) void pack_kernel(
    const float* __restrict__ src, const float* __restrict__ tgt,
    const float* __restrict__ flow,
    float4* __restrict__ pred4, float4* __restrict__ tgt4,
    unsigned* __restrict__ mm, int BN, int BM)
{
    int i = blockIdx.x * 256 + threadIdx.x;
    float lmin = INFV, lmax = -INFV;
    if (i < BN) {
        float x = src[3 * i + 0] + flow[3 * i + 0];
        float y = src[3 * i + 1] + flow[3 * i + 1];
        float z = src[3 * i + 2] + flow[3 * i + 2];
        pred4[i] = make_float4(x, y, z, fmaf(x, x, fmaf(y, y, z * z)));
        lmin = fminf(lmin, x); lmax = fmaxf(lmax, x);
    }
    if (i < BM) {
        float x = tgt[3 * i + 0];
        float y = tgt[3 * i + 1];
        float z = tgt[3 * i + 2];
        tgt4[i] = make_float4(x, y, z, fmaf(x, x, fmaf(y, y, z * z)));
        lmin = fminf(lmin, x); lmax = fmaxf(lmax, x);
    }
#pragma unroll
    for (int off = 32; off > 0; off >>= 1) {
        lmin = fminf(lmin, __shfl_down(lmin, off));
        lmax = fmaxf(lmax, __shfl_down(lmax, off));
    }
    if ((threadIdx.x & 63) == 0) {
        atomicMin(mm + 0, fmap(lmin));
        atomicMax(mm + 1, fmap(lmax));
    }
}

__device__ __forceinline__ int binof(float x, float xmin, float sc) {
    int bn = (int)((x - xmin) * sc);
    return bn < 0 ? 0 : (bn > NB - 1 ? NB - 1 : bn);
}

// counting-sort one point set into x-bins (+ guard fill). blockIdx.x:
// 0=pred b0, 1=pred b1, 2=tgt b0, 3=tgt b1. Within-bin order arbitrary.
// Destination layout per set: [GUARD front | n data | GUARD back].
__global__ __launch_bounds__(1024) void binsort_kernel(
    const float4* __restrict__ pred4, const float4* __restrict__ tgt4,
    float4* __restrict__ ps4, float4* __restrict__ ts4,
    int* __restrict__ goffs, const unsigned* __restrict__ mm, int N, int M)
{
    const int a = blockIdx.x, tid = threadIdx.x;
    const int n = (a < 2) ? N : M;
    const float4* src = (a < 2) ? pred4 + (size_t)a * N : tgt4 + (size_t)(a - 2) * M;
    float4* dst = (a < 2) ? ps4 + (size_t)a * (N + 2 * GUARD)
                          : ts4 + (size_t)(a - 2) * (M + 2 * GUARD);

    __shared__ int hist[NB];
    __shared__ int offs[NB + 1];
    __shared__ int cur[NB];
    const float xmin = funmap(mm[0]);
    const float xmax = funmap(mm[1]);
    const float range = xmax - xmin;
    const float sc = (range > 0.f) ? (float)NB / range : 0.f;

    // guard pads: x = -+1e30 so dxs is huge -> go=false, act dies; w=0.
    for (int i = tid; i < GUARD; i += 1024) {
        dst[i] = make_float4(-1e30f, 0.f, 0.f, 0.f);
        dst[GUARD + n + i] = make_float4(1e30f, 0.f, 0.f, 0.f);
    }

    if (tid < NB) { hist[tid] = 0; cur[tid] = 0; }
    __syncthreads();
    for (int i = tid; i < n; i += 1024)
        atomicAdd(&hist[binof(src[i].x, xmin, sc)], 1);
    __syncthreads();
    for (int off = 1; off < NB; off <<= 1) {
        int t = 0;
        if (tid < NB && tid >= off) t = hist[tid - off];
        __syncthreads();
        if (tid < NB) hist[tid] += t;
        __syncthreads();
    }
    if (tid < NB) offs[tid + 1] = hist[tid];
    if (tid == 0) offs[0] = 0;
    __syncthreads();
    for (int i = tid; i < n; i += 1024) {
        float4 v = src[i];
        int bn = binof(v.x, xmin, sc);
        int slot = atomicAdd(&cur[bn], 1);
        dst[GUARD + offs[bn] + slot] = v;
    }
    if (tid <= NB) goffs[a * (NB + 1) + tid] = offs[tid];
}

// 256 threads = 4 waves; 8 queries/wave, 8 lanes/query (stride 8).
__global__ __launch_bounds__(256, 4) void scan_kernel(
    const float4* __restrict__ ps4, const float4* __restrict__ ts4,
    const int* __restrict__ goffs, const unsigned* __restrict__ mm,
    float* __restrict__ out, int N, int M, float scale_out)
{
    __shared__ float qbuf[QDEPTH * 256];   // 16 KB per-thread queues, stride 256
    __shared__ float wsum[4];

    const int tid = threadIdx.x;
    const int z = blockIdx.y, b = z >> 1, dir = z & 1;
    const int nq = dir ? M : N;
    const int SN = N + 2 * GUARD, SM = M + 2 * GUARD;
    const float4* Qb = dir ? (ts4 + (size_t)b * SM) : (ps4 + (size_t)b * SN);
    const float4* R  = dir ? (ps4 + (size_t)b * SN) : (ts4 + (size_t)b * SM);
    const int oid = dir ? b : 2 + b;       // offsets id of the REF array

    // per-wave chunk remap: mix dense/sparse x-regions across CUs
    const int W = gridDim.x * 4;
    const int wv = blockIdx.x * 4 + (tid >> 6);
    const int c = ((W & (W - 1)) == 0) ? ((wv * 45) & (W - 1)) : wv;
    const int qidx = c * 8 + ((tid >> 3) & 7);
    const bool qv = qidx < nq;
    const int l = tid & 7;                 // lane within octet

    float4 q = Qb[GUARD + (qv ? qidx : 0)];
    const float qx = q.x, q2 = q.w;
    const float nx = -2.f * q.x, ny = -2.f * q.y, nz = -2.f * q.z;

    const float xmin = funmap(mm[0]);
    const float range = funmap(mm[1]) - xmin;
    const float w = range * (1.0f / NB);
    const float sc = (range > 0.f) ? (float)NB / range : 0.f;
    const int start = GUARD + goffs[oid * (NB + 1) + binof(qx, xmin, sc)];

    float s[16];
#pragma unroll
    for (int i = 0; i < 16; ++i) s[i] = INFV;
    float tau     = qv ? INFV : -INFV;     // invalid octets never enqueue
    float rtau_pw = qv ? INFV : -INFV;     // and stop after one group
    int   cnt = 0;
    const float* qb_tid = qbuf + tid;

    // s[] is c-space (c = d2 - q2); tau (c-space, octet-shared) gates
    // enqueues; stop radius converts to d2: sqrt(max(tau+q2,0)) + w.
    // tau = EXACT current union-16th: merge a COPY of the octet's 8 sorted
    // lists (3 halver rounds) -- s itself stays disjoint per lane.
#define DRAIN_ALL() do {                                            \
        drain_batch(s, qb_tid, 0, cnt);                             \
        if (__ballot(cnt > 8)) drain_batch(s, qb_tid, 8, cnt);      \
        cnt = 0;                                                    \
        float t[16], u[16];                                         \
        _Pragma("unroll")                                           \
        for (int i = 0; i < 16; ++i) t[i] = s[i];                   \
        _Pragma("unroll")                                           \
        for (int i = 0; i < 16; ++i) u[i] = __shfl_xor(t[i], 1);    \
        _Pragma("unroll")                                           \
        for (int i = 0; i < 16; ++i) t[i] = fminf(t[i], u[15 - i]); \
        bitonic16(t);                                               \
        _Pragma("unroll")                                           \
        for (int i = 0; i < 16; ++i) u[i] = __shfl_xor(t[i], 2);    \
        _Pragma("unroll")                                           \
        for (int i = 0; i < 16; ++i) t[i] = fminf(t[i], u[15 - i]); \
        bitonic16(t);                                               \
        _Pragma("unroll")                                           \
        for (int i = 0; i < 16; ++i) u[i] = __shfl_xor(t[i], 4);    \
        _Pragma("unroll")                                           \
        for (int i = 0; i < 16; ++i) t[i] = fminf(t[i], u[15 - i]); \
        float mx = t[0];                                            \
        _Pragma("unroll")                                           \
        for (int i = 1; i < 16; ++i) mx = fmaxf(mx, t[i]);          \
        if (qv) { tau = mx;                                         \
                  rtau_pw = sqrtf(fmaxf(mx + q2, 0.0f)) + w; }      \
    } while (0)

    // 8 candidates per lane per group (octet covers 64 consecutive slots).
    // Guard pads make all loads in-bounds: single-path, no bounds checks.
#define PROC8(DIRSGN) do {                                          \
        float4 rr[8];                                               \
        _Pragma("unroll")                                           \
        for (int u = 0; u < 8; ++u)                                 \
            rr[u] = R[p + (DIRSGN) * (u * 8)];                      \
        _Pragma("unroll")                                           \
        for (int u = 0; u < 8; ++u) {                               \
            const float dxs = ((DIRSGN) > 0) ? (rr[u].x - qx)       \
                                             : (qx - rr[u].x);      \
            const bool go = act & (dxs < rtau_pw);                  \
            const float cd = fmaf(nx, rr[u].x, fmaf(ny, rr[u].y,    \
                             fmaf(nz, rr[u].z, rr[u].w)));          \
            qbuf[cnt * 256 + tid] = cd;                             \
            cnt += (go & (cd < tau)) ? 1 : 0;                       \
            act = go;                                               \
        }                                                           \
        p += (DIRSGN) * 64;                                         \
    } while (0)

    // right phase: forced first drain gives near-final tau from the 64
    // x-nearest-on-the-right candidates, then threshold-9 drains.
    {
        int p = start + l;
        bool act = true;
        PROC8(1);
        DRAIN_ALL();
        while (__ballot(act)) {
            PROC8(1);
            if (__ballot(cnt >= QDEPTH - 7)) DRAIN_ALL();
        }
    }
    // left phase: covers everything < start, pruned by right-phase tau.
    {
        int p = start - 8 + l;
        bool act = true;
        while (__ballot(act)) {
            PROC8(-1);
            if (__ballot(cnt >= QDEPTH - 7)) DRAIN_ALL();
        }
    }
    if (__ballot(cnt > 0)) DRAIN_ALL();

#undef PROC8
#undef DRAIN_ALL

    // octet merge (destructive, lists disjoint): after 3 halver rounds all
    // 8 lanes hold the union top-16 multiset (bitonic) -- sum is order-free.
    {
        float u[16];
#pragma unroll
        for (int i = 0; i < 16; ++i) u[i] = __shfl_xor(s[i], 1);
#pragma unroll
        for (int i = 0; i < 16; ++i) s[i] = fminf(s[i], u[15 - i]);
        bitonic16(s);
#pragma unroll
        for (int i = 0; i < 16; ++i) u[i] = __shfl_xor(s[i], 2);
#pragma unroll
        for (int i = 0; i < 16; ++i) s[i] = fminf(s[i], u[15 - i]);
        bitonic16(s);
#pragma unroll
        for (int i = 0; i < 16; ++i) u[i] = __shfl_xor(s[i], 4);
#pragma unroll
        for (int i = 0; i < 16; ++i) s[i] = fminf(s[i], u[15 - i]);
    }

    float acc = 0.0f;
    if (qv) {
#pragma unroll
        for (int i = 0; i < 16; ++i)
            acc += sqrtf(fmaxf(s[i] + q2, 0.0f));   // true d2 = c + |q|^2
    }
#pragma unroll
    for (int off = 32; off > 0; off >>= 1) acc += __shfl_down(acc, off);
    const int lane = tid & 63, wid = tid >> 6;
    if (lane == 0) wsum[wid] = acc;
    __syncthreads();
    if (tid == 0)
        atomicAdd(out, (wsum[0] + wsum[1] + wsum[2] + wsum[3]) * scale_out);
}

extern "C" void kernel_launch(void* const* d_in, const int* in_sizes, int n_in,
                              void* d_out, int out_size, void* d_ws, size_t ws_size,
                              hipStream_t stream) {
    const float* src  = (const float*)d_in[0];   // pc_source [B,N,3]
    const float* tgt  = (const float*)d_in[1];   // pc_target [B,M,3]
    const float* flow = (const float*)d_in[2];   // pred_flow [B,N,3]
    float* out = (float*)d_out;

    const int B = 2;                              // per reference setup
    const int N = in_sizes[0] / (B * 3);
    const int M = in_sizes[1] / (B * 3);
    const int BN = B * N, BM = B * M;

    // workspace: pred4 | tgt4 | ps4 (guarded, sorted) | ts4 | goffs | minmax
    float4* pred4 = (float4*)d_ws;
    float4* tgt4  = pred4 + BN;
    float4* ps4   = tgt4 + BM;
    float4* ts4   = ps4 + (size_t)2 * (N + 2 * GUARD);
    int*    goffs = (int*)(ts4 + (size_t)2 * (M + 2 * GUARD));
    unsigned* mm  = (unsigned*)(goffs + 4 * (NB + 1));

    init_kernel<<<1, 64, 0, stream>>>(out, mm);

    int maxBP = (BN > BM) ? BN : BM;
    pack_kernel<<<(maxBP + 255) / 256, 256, 0, stream>>>(
        src, tgt, flow, pred4, tgt4, mm, BN, BM);

    binsort_kernel<<<4, 1024, 0, stream>>>(pred4, tgt4, ps4, ts4, goffs, mm, N, M);

    int maxq = (N > M) ? N : M;
    dim3 grid((maxq + 31) / 32, 2 * B);
    float scale_out = 1.0f / (8.0f * 16.0f * (float)B * (float)N);
    scan_kernel<<<grid, 256, 0, stream>>>(ps4, ts4, goffs, mm, out, N, M, scale_out);
}

// Round 5
// 166.651 us; speedup vs baseline: 1.4777x; 1.1066x over previous
//
#include <hip/hip_runtime.h>
#include <math.h>

// Chamfer k-NN (k=16, L2), R18: GROUP=16 for full residency + guard fix.
// R17 post-mortem: VGPR=44, LDS=16.9KB allow 8 blocks/CU, but grid was only
// 1024 blocks -> 4/CU -> 16 waves/CU cap -> 23% occupancy, latency-bound.
// Also absmax 0.0078 (near-fail): right-guard entries (w=0) produced
// cd = -2*qx*1e30 (huge negative) under tau=INF in the first forced group ->
// fake zero-distance neighbors for end-of-array queries.
// Fixes:
//  - GROUP=16 lanes/query, 4 queries/wave: 2048 blocks = 8 blocks/CU
//    all-resident (32 waves/CU). Per-lane enqueues halve -> fewer drains.
//  - guards carry .w=INFV so cd rounds to exactly INFV -> never enqueued
//    even when tau=INFV; act-chain still dies on dxs once rtau is finite.
//    GUARD=320 >= 255 worst-case penetration (127 straddle + 128 one group).
//  - exact union-tau now 4 halver rounds (xor 1,2,4,8) on a COPY at drains.
// Pipeline: init -> pack (pred4/tgt4 + x-min/max) -> binsort (NB=512
// counting sort + guards) -> scan (two-sided, stop dx >= sqrt(tau_d2)+w).

#define INFV    3.0e38f
#define QDEPTH  16
#define NB      512
#define GUARD   320

__device__ __forceinline__ void ce(float& a, float& b) {
    float lo = fminf(a, b);
    b = fmaxf(a, b);
    a = lo;
}

// bitonic merge-sort of a bitonic 16-seq (stages 8,4,2,1 = 32 CE), ascending
__device__ __forceinline__ void bitonic16(float (&s)[16]) {
    ce(s[0],s[8]);  ce(s[1],s[9]);  ce(s[2],s[10]); ce(s[3],s[11]);
    ce(s[4],s[12]); ce(s[5],s[13]); ce(s[6],s[14]); ce(s[7],s[15]);
    ce(s[0],s[4]);  ce(s[1],s[5]);  ce(s[2],s[6]);  ce(s[3],s[7]);
    ce(s[8],s[12]); ce(s[9],s[13]); ce(s[10],s[14]);ce(s[11],s[15]);
    ce(s[0],s[2]);  ce(s[1],s[3]);  ce(s[4],s[6]);  ce(s[5],s[7]);
    ce(s[8],s[10]); ce(s[9],s[11]); ce(s[12],s[14]);ce(s[13],s[15]);
    ce(s[0],s[1]);  ce(s[2],s[3]);  ce(s[4],s[5]);  ce(s[6],s[7]);
    ce(s[8],s[9]);  ce(s[10],s[11]);ce(s[12],s[13]);ce(s[14],s[15]);
}

// Merge up to 8 queued values (qb[(base+i)*256], i<cnt-base) into sorted s[16].
__device__ __forceinline__ void drain_batch(float (&s)[16], const float* qb,
                                            int base, int cnt)
{
    float q[8];
#pragma unroll
    for (int i = 0; i < 8; ++i) {
        float v = qb[(base + i) * 256];
        q[i] = (base + i < cnt) ? v : INFV;
    }
    // sort8 ascending -- Batcher odd-even, 19 CE
    ce(q[0],q[1]); ce(q[2],q[3]); ce(q[4],q[5]); ce(q[6],q[7]);
    ce(q[0],q[2]); ce(q[1],q[3]); ce(q[4],q[6]); ce(q[5],q[7]);
    ce(q[1],q[2]); ce(q[5],q[6]);
    ce(q[0],q[4]); ce(q[1],q[5]); ce(q[2],q[6]); ce(q[3],q[7]);
    ce(q[2],q[4]); ce(q[3],q[5]);
    ce(q[1],q[2]); ce(q[3],q[4]); ce(q[5],q[6]);
    // bitonic halver vs sorted s[16]
#pragma unroll
    for (int i = 0; i < 8; ++i) s[8 + i] = fminf(s[8 + i], q[7 - i]);
    bitonic16(s);
}

// order-preserving float<->uint map for atomicMin/Max
__device__ __forceinline__ unsigned fmap(float f) {
    unsigned u = __float_as_uint(f);
    return (u & 0x80000000u) ? ~u : (u | 0x80000000u);
}
__device__ __forceinline__ float funmap(unsigned u) {
    unsigned v = (u & 0x80000000u) ? (u & 0x7fffffffu) : ~u;
    return __uint_as_float(v);
}

__global__ void init_kernel(float* __restrict__ out, unsigned* __restrict__ mm) {
    if (threadIdx.x == 0) {
        out[0] = 0.0f;          // replaces memset (poisoned 0xAA)
        mm[0] = 0xFFFFFFFFu;    // min sentinel (mapped order)
        mm[1] = 0u;             // max sentinel
    }
}

__global__ __launch_bounds__(256) void pack_kernel(
    const float* __restrict__ src, const float* __restrict__ tgt,
    const float* __restrict__ flow,
    float4* __restrict__ pred4, float4* __restrict__ tgt4,
    unsigned* __restrict__ mm, int BN, int BM)
{
    int i = blockIdx.x * 256 + threadIdx.x;
    float lmin = INFV, lmax = -INFV;
    if (i < BN) {
        float x = src[3 * i + 0] + flow[3 * i + 0];
        float y = src[3 * i + 1] + flow[3 * i + 1];
        float z = src[3 * i + 2] + flow[3 * i + 2];
        pred4[i] = make_float4(x, y, z, fmaf(x, x, fmaf(y, y, z * z)));
        lmin = fminf(lmin, x); lmax = fmaxf(lmax, x);
    }
    if (i < BM) {
        float x = tgt[3 * i + 0];
        float y = tgt[3 * i + 1];
        float z = tgt[3 * i + 2];
        tgt4[i] = make_float4(x, y, z, fmaf(x, x, fmaf(y, y, z * z)));
        lmin = fminf(lmin, x); lmax = fmaxf(lmax, x);
    }
#pragma unroll
    for (int off = 32; off > 0; off >>= 1) {
        lmin = fminf(lmin, __shfl_down(lmin, off));
        lmax = fmaxf(lmax, __shfl_down(lmax, off));
    }
    if ((threadIdx.x & 63) == 0) {
        atomicMin(mm + 0, fmap(lmin));
        atomicMax(mm + 1, fmap(lmax));
    }
}

__device__ __forceinline__ int binof(float x, float xmin, float sc) {
    int bn = (int)((x - xmin) * sc);
    return bn < 0 ? 0 : (bn > NB - 1 ? NB - 1 : bn);
}

// counting-sort one point set into x-bins (+ guard fill). blockIdx.x:
// 0=pred b0, 1=pred b1, 2=tgt b0, 3=tgt b1. Within-bin order arbitrary.
// Destination layout per set: [GUARD front | n data | GUARD back].
__global__ __launch_bounds__(1024) void binsort_kernel(
    const float4* __restrict__ pred4, const float4* __restrict__ tgt4,
    float4* __restrict__ ps4, float4* __restrict__ ts4,
    int* __restrict__ goffs, const unsigned* __restrict__ mm, int N, int M)
{
    const int a = blockIdx.x, tid = threadIdx.x;
    const int n = (a < 2) ? N : M;
    const float4* src = (a < 2) ? pred4 + (size_t)a * N : tgt4 + (size_t)(a - 2) * M;
    float4* dst = (a < 2) ? ps4 + (size_t)a * (N + 2 * GUARD)
                          : ts4 + (size_t)(a - 2) * (M + 2 * GUARD);

    __shared__ int hist[NB];
    __shared__ int offs[NB + 1];
    __shared__ int cur[NB];
    const float xmin = funmap(mm[0]);
    const float xmax = funmap(mm[1]);
    const float range = xmax - xmin;
    const float sc = (range > 0.f) ? (float)NB / range : 0.f;

    // guard pads: x=+-1e30 kills the act-chain once rtau is finite; w=INFV
    // makes cd round to exactly INFV -> never enqueued even under tau=INFV.
    for (int i = tid; i < GUARD; i += 1024) {
        dst[i] = make_float4(-1e30f, 0.f, 0.f, INFV);
        dst[GUARD + n + i] = make_float4(1e30f, 0.f, 0.f, INFV);
    }

    if (tid < NB) { hist[tid] = 0; cur[tid] = 0; }
    __syncthreads();
    for (int i = tid; i < n; i += 1024)
        atomicAdd(&hist[binof(src[i].x, xmin, sc)], 1);
    __syncthreads();
    for (int off = 1; off < NB; off <<= 1) {
        int t = 0;
        if (tid < NB && tid >= off) t = hist[tid - off];
        __syncthreads();
        if (tid < NB) hist[tid] += t;
        __syncthreads();
    }
    if (tid < NB) offs[tid + 1] = hist[tid];
    if (tid == 0) offs[0] = 0;
    __syncthreads();
    for (int i = tid; i < n; i += 1024) {
        float4 v = src[i];
        int bn = binof(v.x, xmin, sc);
        int slot = atomicAdd(&cur[bn], 1);
        dst[GUARD + offs[bn] + slot] = v;
    }
    if (tid <= NB) goffs[a * (NB + 1) + tid] = offs[tid];
}

// 256 threads = 4 waves; 4 queries/wave, 16 lanes/query (stride 16).
__global__ __launch_bounds__(256, 4) void scan_kernel(
    const float4* __restrict__ ps4, const float4* __restrict__ ts4,
    const int* __restrict__ goffs, const unsigned* __restrict__ mm,
    float* __restrict__ out, int N, int M, float scale_out)
{
    __shared__ float qbuf[QDEPTH * 256];   // 16 KB per-thread queues, stride 256
    __shared__ float wsum[4];

    const int tid = threadIdx.x;
    const int z = blockIdx.y, b = z >> 1, dir = z & 1;
    const int nq = dir ? M : N;
    const int SN = N + 2 * GUARD, SM = M + 2 * GUARD;
    const float4* Qb = dir ? (ts4 + (size_t)b * SM) : (ps4 + (size_t)b * SN);
    const float4* R  = dir ? (ps4 + (size_t)b * SN) : (ts4 + (size_t)b * SM);
    const int oid = dir ? b : 2 + b;       // offsets id of the REF array

    // per-wave chunk remap: mix dense/sparse x-regions across CUs
    const int W = gridDim.x * 4;
    const int wv = blockIdx.x * 4 + (tid >> 6);
    const int c = ((W & (W - 1)) == 0) ? ((wv * 45) & (W - 1)) : wv;
    const int qidx = c * 4 + ((tid >> 4) & 3);   // 4 consecutive queries/wave
    const bool qv = qidx < nq;
    const int l = tid & 15;                // lane within 16-lane group

    float4 q = Qb[GUARD + (qv ? qidx : 0)];
    const float qx = q.x, q2 = q.w;
    const float nx = -2.f * q.x, ny = -2.f * q.y, nz = -2.f * q.z;

    const float xmin = funmap(mm[0]);
    const float range = funmap(mm[1]) - xmin;
    const float w = range * (1.0f / NB);
    const float sc = (range > 0.f) ? (float)NB / range : 0.f;
    const int start = GUARD + goffs[oid * (NB + 1) + binof(qx, xmin, sc)];

    float s[16];
#pragma unroll
    for (int i = 0; i < 16; ++i) s[i] = INFV;
    float tau     = qv ? INFV : -INFV;     // invalid groups never enqueue
    float rtau_pw = qv ? INFV : -INFV;     // and stop after one group
    int   cnt = 0;
    const float* qb_tid = qbuf + tid;

    // s[] is c-space (c = d2 - q2); tau (c-space, group-shared) gates
    // enqueues; stop radius converts to d2: sqrt(max(tau+q2,0)) + w.
    // tau = EXACT current union-16th: merge a COPY of the group's 16 sorted
    // lists (4 halver rounds) -- s itself stays disjoint per lane.
#define DRAIN_ALL() do {                                            \
        drain_batch(s, qb_tid, 0, cnt);                             \
        if (__ballot(cnt > 8)) drain_batch(s, qb_tid, 8, cnt);      \
        cnt = 0;                                                    \
        float t[16], u[16];                                         \
        _Pragma("unroll")                                           \
        for (int i = 0; i < 16; ++i) t[i] = s[i];                   \
        _Pragma("unroll")                                           \
        for (int i = 0; i < 16; ++i) u[i] = __shfl_xor(t[i], 1);    \
        _Pragma("unroll")                                           \
        for (int i = 0; i < 16; ++i) t[i] = fminf(t[i], u[15 - i]); \
        bitonic16(t);                                               \
        _Pragma("unroll")                                           \
        for (int i = 0; i < 16; ++i) u[i] = __shfl_xor(t[i], 2);    \
        _Pragma("unroll")                                           \
        for (int i = 0; i < 16; ++i) t[i] = fminf(t[i], u[15 - i]); \
        bitonic16(t);                                               \
        _Pragma("unroll")                                           \
        for (int i = 0; i < 16; ++i) u[i] = __shfl_xor(t[i], 4);    \
        _Pragma("unroll")                                           \
        for (int i = 0; i < 16; ++i) t[i] = fminf(t[i], u[15 - i]); \
        bitonic16(t);                                               \
        _Pragma("unroll")                                           \
        for (int i = 0; i < 16; ++i) u[i] = __shfl_xor(t[i], 8);    \
        _Pragma("unroll")                                           \
        for (int i = 0; i < 16; ++i) t[i] = fminf(t[i], u[15 - i]); \
        float mx = t[0];                                            \
        _Pragma("unroll")                                           \
        for (int i = 1; i < 16; ++i) mx = fmaxf(mx, t[i]);          \
        if (qv) { tau = mx;                                         \
                  rtau_pw = sqrtf(fmaxf(mx + q2, 0.0f)) + w; }      \
    } while (0)

    // 8 candidates per lane per group (group covers 128 consecutive slots).
    // Guard pads make all loads in-bounds: single-path, no bounds checks.
#define PROC8(DIRSGN) do {                                          \
        float4 rr[8];                                               \
        _Pragma("unroll")                                           \
        for (int u = 0; u < 8; ++u)                                 \
            rr[u] = R[p + (DIRSGN) * (u * 16)];                     \
        _Pragma("unroll")                                           \
        for (int u = 0; u < 8; ++u) {                               \
            const float dxs = ((DIRSGN) > 0) ? (rr[u].x - qx)       \
                                             : (qx - rr[u].x);      \
            const bool go = act & (dxs < rtau_pw);                  \
            const float cd = fmaf(nx, rr[u].x, fmaf(ny, rr[u].y,    \
                             fmaf(nz, rr[u].z, rr[u].w)));          \
            qbuf[cnt * 256 + tid] = cd;                             \
            cnt += (go & (cd < tau)) ? 1 : 0;                       \
            act = go;                                               \
        }                                                           \
        p += (DIRSGN) * 128;                                        \
    } while (0)

    // right phase: forced first drain gives near-final tau from the 128
    // x-nearest-on-the-right candidates, then threshold drains.
    {
        int p = start + l;
        bool act = true;
        PROC8(1);
        DRAIN_ALL();
        while (__ballot(act)) {
            PROC8(1);
            if (__ballot(cnt >= QDEPTH - 7)) DRAIN_ALL();
        }
    }
    // left phase: covers everything < start, pruned by right-phase tau.
    {
        int p = start - 16 + l;
        bool act = true;
        while (__ballot(act)) {
            PROC8(-1);
            if (__ballot(cnt >= QDEPTH - 7)) DRAIN_ALL();
        }
    }
    if (__ballot(cnt > 0)) DRAIN_ALL();

#undef PROC8
#undef DRAIN_ALL

    // group merge (destructive, lists disjoint): after 4 halver rounds all
    // 16 lanes hold the union top-16 multiset (bitonic) -- sum is order-free.
    {
        float u[16];
#pragma unroll
        for (int i = 0; i < 16; ++i) u[i] = __shfl_xor(s[i], 1);
#pragma unroll
        for (int i = 0; i < 16; ++i) s[i] = fminf(s[i], u[15 - i]);
        bitonic16(s);
#pragma unroll
        for (int i = 0; i < 16; ++i) u[i] = __shfl_xor(s[i], 2);
#pragma unroll
        for (int i = 0; i < 16; ++i) s[i] = fminf(s[i], u[15 - i]);
        bitonic16(s);
#pragma unroll
        for (int i = 0; i < 16; ++i) u[i] = __shfl_xor(s[i], 4);
#pragma unroll
        for (int i = 0; i < 16; ++i) s[i] = fminf(s[i], u[15 - i]);
        bitonic16(s);
#pragma unroll
        for (int i = 0; i < 16; ++i) u[i] = __shfl_xor(s[i], 8);
#pragma unroll
        for (int i = 0; i < 16; ++i) s[i] = fminf(s[i], u[15 - i]);
    }

    float acc = 0.0f;
    if (qv) {
#pragma unroll
        for (int i = 0; i < 16; ++i)
            acc += sqrtf(fmaxf(s[i] + q2, 0.0f));   // true d2 = c + |q|^2
    }
#pragma unroll
    for (int off = 32; off > 0; off >>= 1) acc += __shfl_down(acc, off);
    const int lane = tid & 63, wid = tid >> 6;
    if (lane == 0) wsum[wid] = acc;
    __syncthreads();
    if (tid == 0)
        atomicAdd(out, (wsum[0] + wsum[1] + wsum[2] + wsum[3]) * scale_out);
}

extern "C" void kernel_launch(void* const* d_in, const int* in_sizes, int n_in,
                              void* d_out, int out_size, void* d_ws, size_t ws_size,
                              hipStream_t stream) {
    const float* src  = (const float*)d_in[0];   // pc_source [B,N,3]
    const float* tgt  = (const float*)d_in[1];   // pc_target [B,M,3]
    const float* flow = (const float*)d_in[2];   // pred_flow [B,N,3]
    float* out = (float*)d_out;

    const int B = 2;                              // per reference setup
    const int N = in_sizes[0] / (B * 3);
    const int M = in_sizes[1] / (B * 3);
    const int BN = B * N, BM = B * M;

    // workspace: pred4 | tgt4 | ps4 (guarded, sorted) | ts4 | goffs | minmax
    float4* pred4 = (float4*)d_ws;
    float4* tgt4  = pred4 + BN;
    float4* ps4   = tgt4 + BM;
    float4* ts4   = ps4 + (size_t)2 * (N + 2 * GUARD);
    int*    goffs = (int*)(ts4 + (size_t)2 * (M + 2 * GUARD));
    unsigned* mm  = (unsigned*)(goffs + 4 * (NB + 1));

    init_kernel<<<1, 64, 0, stream>>>(out, mm);

    int maxBP = (BN > BM) ? BN : BM;
    pack_kernel<<<(maxBP + 255) / 256, 256, 0, stream>>>(
        src, tgt, flow, pred4, tgt4, mm, BN, BM);

    binsort_kernel<<<4, 1024, 0, stream>>>(pred4, tgt4, ps4, ts4, goffs, mm, N, M);

    int maxq = (N > M) ? N : M;
    dim3 grid((maxq + 15) / 16, 2 * B);   // 16 queries per 256-thr block
    float scale_out = 1.0f / (16.0f * 16.0f * (float)B * (float)N);
    scan_kernel<<<grid, 256, 0, stream>>>(ps4, ts4, goffs, mm, out, N, M, scale_out);
}

// Round 6
// 166.544 us; speedup vs baseline: 1.4786x; 1.0006x over previous
//
#include <hip/hip_runtime.h>
#include <math.h>

// Chamfer k-NN (k=16, L2), R19: centered probe + frozen tau + cheap drains.
// R18 post-mortem: scan VALU-time ROSE to 65us -- the 4-round exact tau-merge
// (~450 wave-inst) ran at every drain (~4-5/query) and dominated; one-sided
// initial probe gave tau0 ~1.5x final -> over-scan both phases. ~58us of
// non-scan overhead (init launch + 18-barrier binsort scan).
// Fixes (all exact):
//  - centered 256-slot probe (128 right + 128 left, cnt<=QDEPTH=16) before
//    the forced drain -> tau0 = union-16th of the 256 x-nearest (near-final).
//    Guard penetration <= 256 <= GUARD=320 on both sides, no OOB.
//  - tau frozen after 2 full merges: stale tau is still an upper bound on
//    the final union-16th -> exact; later drains are drain_batch-only.
//  - init kernel removed: hipMemsetAsync(out,0) + hipMemsetAsync(mm,0xFF);
//    mm[1] = min fmap(-x) so both sentinels are 0xFF bytes.
//  - binsort prefix scan: single-wave shfl scan (2 barriers, was 18).
// Pipeline: memsets -> pack (pred4/tgt4 + x-min/max) -> binsort (NB=512
// counting sort + guards) -> scan (two-sided, stop dx >= sqrt(tau_d2)+w).

#define INFV    3.0e38f
#define QDEPTH  16
#define NB      512
#define GUARD   320

__device__ __forceinline__ void ce(float& a, float& b) {
    float lo = fminf(a, b);
    b = fmaxf(a, b);
    a = lo;
}

// bitonic merge-sort of a bitonic 16-seq (stages 8,4,2,1 = 32 CE), ascending
__device__ __forceinline__ void bitonic16(float (&s)[16]) {
    ce(s[0],s[8]);  ce(s[1],s[9]);  ce(s[2],s[10]); ce(s[3],s[11]);
    ce(s[4],s[12]); ce(s[5],s[13]); ce(s[6],s[14]); ce(s[7],s[15]);
    ce(s[0],s[4]);  ce(s[1],s[5]);  ce(s[2],s[6]);  ce(s[3],s[7]);
    ce(s[8],s[12]); ce(s[9],s[13]); ce(s[10],s[14]);ce(s[11],s[15]);
    ce(s[0],s[2]);  ce(s[1],s[3]);  ce(s[4],s[6]);  ce(s[5],s[7]);
    ce(s[8],s[10]); ce(s[9],s[11]); ce(s[12],s[14]);ce(s[13],s[15]);
    ce(s[0],s[1]);  ce(s[2],s[3]);  ce(s[4],s[5]);  ce(s[6],s[7]);
    ce(s[8],s[9]);  ce(s[10],s[11]);ce(s[12],s[13]);ce(s[14],s[15]);
}

// Merge up to 8 queued values (qb[(base+i)*256], i<cnt-base) into sorted s[16].
__device__ __forceinline__ void drain_batch(float (&s)[16], const float* qb,
                                            int base, int cnt)
{
    float q[8];
#pragma unroll
    for (int i = 0; i < 8; ++i) {
        float v = qb[(base + i) * 256];
        q[i] = (base + i < cnt) ? v : INFV;
    }
    // sort8 ascending -- Batcher odd-even, 19 CE
    ce(q[0],q[1]); ce(q[2],q[3]); ce(q[4],q[5]); ce(q[6],q[7]);
    ce(q[0],q[2]); ce(q[1],q[3]); ce(q[4],q[6]); ce(q[5],q[7]);
    ce(q[1],q[2]); ce(q[5],q[6]);
    ce(q[0],q[4]); ce(q[1],q[5]); ce(q[2],q[6]); ce(q[3],q[7]);
    ce(q[2],q[4]); ce(q[3],q[5]);
    ce(q[1],q[2]); ce(q[3],q[4]); ce(q[5],q[6]);
    // bitonic halver vs sorted s[16]
#pragma unroll
    for (int i = 0; i < 8; ++i) s[8 + i] = fminf(s[8 + i], q[7 - i]);
    bitonic16(s);
}

// order-preserving float<->uint map for atomicMin
__device__ __forceinline__ unsigned fmap(float f) {
    unsigned u = __float_as_uint(f);
    return (u & 0x80000000u) ? ~u : (u | 0x80000000u);
}
__device__ __forceinline__ float funmap(unsigned u) {
    unsigned v = (u & 0x80000000u) ? (u & 0x7fffffffu) : ~u;
    return __uint_as_float(v);
}

__global__ __launch_bounds__(256) void pack_kernel(
    const float* __restrict__ src, const float* __restrict__ tgt,
    const float* __restrict__ flow,
    float4* __restrict__ pred4, float4* __restrict__ tgt4,
    unsigned* __restrict__ mm, int BN, int BM)
{
    int i = blockIdx.x * 256 + threadIdx.x;
    float lmin = INFV, lmax = -INFV;
    if (i < BN) {
        float x = src[3 * i + 0] + flow[3 * i + 0];
        float y = src[3 * i + 1] + flow[3 * i + 1];
        float z = src[3 * i + 2] + flow[3 * i + 2];
        pred4[i] = make_float4(x, y, z, fmaf(x, x, fmaf(y, y, z * z)));
        lmin = fminf(lmin, x); lmax = fmaxf(lmax, x);
    }
    if (i < BM) {
        float x = tgt[3 * i + 0];
        float y = tgt[3 * i + 1];
        float z = tgt[3 * i + 2];
        tgt4[i] = make_float4(x, y, z, fmaf(x, x, fmaf(y, y, z * z)));
        lmin = fminf(lmin, x); lmax = fmaxf(lmax, x);
    }
#pragma unroll
    for (int off = 32; off > 0; off >>= 1) {
        lmin = fminf(lmin, __shfl_down(lmin, off));
        lmax = fmaxf(lmax, __shfl_down(lmax, off));
    }
    if ((threadIdx.x & 63) == 0) {
        atomicMin(mm + 0, fmap(lmin));     // xmin
        atomicMin(mm + 1, fmap(-lmax));    // -xmax (min-form; 0xFF sentinel)
    }
}

__device__ __forceinline__ int binof(float x, float xmin, float sc) {
    int bn = (int)((x - xmin) * sc);
    return bn < 0 ? 0 : (bn > NB - 1 ? NB - 1 : bn);
}

// counting-sort one point set into x-bins (+ guard fill). blockIdx.x:
// 0=pred b0, 1=pred b1, 2=tgt b0, 3=tgt b1. Within-bin order arbitrary.
// Destination layout per set: [GUARD front | n data | GUARD back].
__global__ __launch_bounds__(1024) void binsort_kernel(
    const float4* __restrict__ pred4, const float4* __restrict__ tgt4,
    float4* __restrict__ ps4, float4* __restrict__ ts4,
    int* __restrict__ goffs, const unsigned* __restrict__ mm, int N, int M)
{
    const int a = blockIdx.x, tid = threadIdx.x;
    const int n = (a < 2) ? N : M;
    const float4* src = (a < 2) ? pred4 + (size_t)a * N : tgt4 + (size_t)(a - 2) * M;
    float4* dst = (a < 2) ? ps4 + (size_t)a * (N + 2 * GUARD)
                          : ts4 + (size_t)(a - 2) * (M + 2 * GUARD);

    __shared__ int hist[NB];
    __shared__ int offs[NB + 1];
    __shared__ int cur[NB];
    const float xmin = funmap(mm[0]);
    const float xmax = -funmap(mm[1]);
    const float range = xmax - xmin;
    const float sc = (range > 0.f) ? (float)NB / range : 0.f;

    // guard pads: x=+-1e30 kills the act-chain once rtau is finite; w=INFV
    // makes cd round to exactly INFV -> never enqueued even under tau=INFV.
    for (int i = tid; i < GUARD; i += 1024) {
        dst[i] = make_float4(-1e30f, 0.f, 0.f, INFV);
        dst[GUARD + n + i] = make_float4(1e30f, 0.f, 0.f, INFV);
    }

    if (tid < NB) { hist[tid] = 0; cur[tid] = 0; }
    __syncthreads();
    for (int i = tid; i < n; i += 1024)
        atomicAdd(&hist[binof(src[i].x, xmin, sc)], 1);
    __syncthreads();
    // single-wave prefix scan over NB=512 bins: 8 bins/lane serial prefix,
    // then 64-lane shfl_up exclusive scan of lane totals. 2 barriers total.
    if (tid < 64) {
        const int base = tid * 8;
        int inc[8];
        int run = 0;
#pragma unroll
        for (int i = 0; i < 8; ++i) { run += hist[base + i]; inc[i] = run; }
        int x = run;
#pragma unroll
        for (int off = 1; off < 64; off <<= 1) {
            int y = __shfl_up(x, off);
            if (tid >= (unsigned)off) x += y;
        }
        const int excl = x - run;
#pragma unroll
        for (int i = 0; i < 8; ++i) offs[base + 1 + i] = excl + inc[i];
        if (tid == 0) offs[0] = 0;
    }
    __syncthreads();
    for (int i = tid; i < n; i += 1024) {
        float4 v = src[i];
        int bn = binof(v.x, xmin, sc);
        int slot = atomicAdd(&cur[bn], 1);
        dst[GUARD + offs[bn] + slot] = v;
    }
    if (tid <= NB) goffs[a * (NB + 1) + tid] = offs[tid];
}

// 256 threads = 4 waves; 4 queries/wave, 16 lanes/query (stride 16).
__global__ __launch_bounds__(256, 4) void scan_kernel(
    const float4* __restrict__ ps4, const float4* __restrict__ ts4,
    const int* __restrict__ goffs, const unsigned* __restrict__ mm,
    float* __restrict__ out, int N, int M, float scale_out)
{
    __shared__ float qbuf[QDEPTH * 256];   // 16 KB per-thread queues, stride 256
    __shared__ float wsum[4];

    const int tid = threadIdx.x;
    const int z = blockIdx.y, b = z >> 1, dir = z & 1;
    const int nq = dir ? M : N;
    const int SN = N + 2 * GUARD, SM = M + 2 * GUARD;
    const float4* Qb = dir ? (ts4 + (size_t)b * SM) : (ps4 + (size_t)b * SN);
    const float4* R  = dir ? (ps4 + (size_t)b * SN) : (ts4 + (size_t)b * SM);
    const int oid = dir ? b : 2 + b;       // offsets id of the REF array

    // per-wave chunk remap: mix dense/sparse x-regions across CUs
    const int W = gridDim.x * 4;
    const int wv = blockIdx.x * 4 + (tid >> 6);
    const int c = ((W & (W - 1)) == 0) ? ((wv * 45) & (W - 1)) : wv;
    const int qidx = c * 4 + ((tid >> 4) & 3);   // 4 consecutive queries/wave
    const bool qv = qidx < nq;
    const int l = tid & 15;                // lane within 16-lane group

    float4 q = Qb[GUARD + (qv ? qidx : 0)];
    const float qx = q.x, q2 = q.w;
    const float nx = -2.f * q.x, ny = -2.f * q.y, nz = -2.f * q.z;

    const float xmin = funmap(mm[0]);
    const float range = -funmap(mm[1]) - xmin;
    const float w = range * (1.0f / NB);
    const float sc = (range > 0.f) ? (float)NB / range : 0.f;
    const int start = GUARD + goffs[oid * (NB + 1) + binof(qx, xmin, sc)];

    float s[16];
#pragma unroll
    for (int i = 0; i < 16; ++i) s[i] = INFV;
    float tau     = qv ? INFV : -INFV;     // invalid groups never enqueue
    float rtau_pw = qv ? INFV : -INFV;     // and stop after one group
    int   cnt = 0;
    int   tauLeft = 2;                     // full tau-merges remaining
    const float* qb_tid = qbuf + tid;

    // s[] is c-space (c = d2 - q2); tau (c-space, group-shared) gates
    // enqueues; stop radius converts to d2: sqrt(max(tau+q2,0)) + w.
    // tau = exact union-16th at merge time; FROZEN after 2 merges (stale tau
    // is still an upper bound on the final union-16th -> pruning exact).
#define DRAIN_ALL() do {                                            \
        drain_batch(s, qb_tid, 0, cnt);                             \
        if (__ballot(cnt > 8)) drain_batch(s, qb_tid, 8, cnt);      \
        cnt = 0;                                                    \
        if (tauLeft > 0) {                                          \
            --tauLeft;                                              \
            float t[16], u[16];                                     \
            _Pragma("unroll")                                       \
            for (int i = 0; i < 16; ++i) t[i] = s[i];               \
            _Pragma("unroll")                                       \
            for (int i = 0; i < 16; ++i) u[i] = __shfl_xor(t[i], 1);\
            _Pragma("unroll")                                       \
            for (int i = 0; i < 16; ++i) t[i] = fminf(t[i], u[15 - i]); \
            bitonic16(t);                                           \
            _Pragma("unroll")                                       \
            for (int i = 0; i < 16; ++i) u[i] = __shfl_xor(t[i], 2);\
            _Pragma("unroll")                                       \
            for (int i = 0; i < 16; ++i) t[i] = fminf(t[i], u[15 - i]); \
            bitonic16(t);                                           \
            _Pragma("unroll")                                       \
            for (int i = 0; i < 16; ++i) u[i] = __shfl_xor(t[i], 4);\
            _Pragma("unroll")                                       \
            for (int i = 0; i < 16; ++i) t[i] = fminf(t[i], u[15 - i]); \
            bitonic16(t);                                           \
            _Pragma("unroll")                                       \
            for (int i = 0; i < 16; ++i) u[i] = __shfl_xor(t[i], 8);\
            _Pragma("unroll")                                       \
            for (int i = 0; i < 16; ++i) t[i] = fminf(t[i], u[15 - i]); \
            float mx = t[0];                                        \
            _Pragma("unroll")                                       \
            for (int i = 1; i < 16; ++i) mx = fmaxf(mx, t[i]);      \
            if (qv) { tau = mx;                                     \
                      rtau_pw = sqrtf(fmaxf(mx + q2, 0.0f)) + w; }  \
        }                                                           \
    } while (0)

    // 8 candidates per lane per group (group covers 128 consecutive slots).
    // Guard pads make all loads in-bounds: single-path, no bounds checks.
#define PROC8(P, ACT, DIRSGN) do {                                  \
        float4 rr[8];                                               \
        _Pragma("unroll")                                           \
        for (int u = 0; u < 8; ++u)                                 \
            rr[u] = R[(P) + (DIRSGN) * (u * 16)];                   \
        _Pragma("unroll")                                           \
        for (int u = 0; u < 8; ++u) {                               \
            const float dxs = ((DIRSGN) > 0) ? (rr[u].x - qx)       \
                                             : (qx - rr[u].x);      \
            const bool go = (ACT) & (dxs < rtau_pw);                \
            const float cd = fmaf(nx, rr[u].x, fmaf(ny, rr[u].y,    \
                             fmaf(nz, rr[u].z, rr[u].w)));          \
            qbuf[cnt * 256 + tid] = cd;                             \
            cnt += (go & (cd < tau)) ? 1 : 0;                       \
            (ACT) = go;                                             \
        }                                                           \
        (P) += (DIRSGN) * 128;                                      \
    } while (0)

    int  pr = start + l;
    int  pl = start - 16 + l;
    bool actR = true, actL = true;

    // centered probe: 128 right + 128 left (cnt <= 16 = QDEPTH exactly),
    // then forced FULL drain -> tau ~ final union-16th immediately.
    PROC8(pr, actR, 1);
    PROC8(pl, actL, -1);
    DRAIN_ALL();

    // right phase (continues at start+128)
    while (__ballot(actR)) {
        PROC8(pr, actR, 1);
        if (__ballot(cnt >= QDEPTH - 7)) DRAIN_ALL();
    }
    // left phase (continues at start-144+l); pruned by near-final tau
    while (__ballot(actL)) {
        PROC8(pl, actL, -1);
        if (__ballot(cnt >= QDEPTH - 7)) DRAIN_ALL();
    }
    if (__ballot(cnt > 0)) DRAIN_ALL();

#undef PROC8
#undef DRAIN_ALL

    // group merge (destructive, lists disjoint): after 4 halver rounds all
    // 16 lanes hold the union top-16 multiset (bitonic) -- sum is order-free.
    {
        float u[16];
#pragma unroll
        for (int i = 0; i < 16; ++i) u[i] = __shfl_xor(s[i], 1);
#pragma unroll
        for (int i = 0; i < 16; ++i) s[i] = fminf(s[i], u[15 - i]);
        bitonic16(s);
#pragma unroll
        for (int i = 0; i < 16; ++i) u[i] = __shfl_xor(s[i], 2);
#pragma unroll
        for (int i = 0; i < 16; ++i) s[i] = fminf(s[i], u[15 - i]);
        bitonic16(s);
#pragma unroll
        for (int i = 0; i < 16; ++i) u[i] = __shfl_xor(s[i], 4);
#pragma unroll
        for (int i = 0; i < 16; ++i) s[i] = fminf(s[i], u[15 - i]);
        bitonic16(s);
#pragma unroll
        for (int i = 0; i < 16; ++i) u[i] = __shfl_xor(s[i], 8);
#pragma unroll
        for (int i = 0; i < 16; ++i) s[i] = fminf(s[i], u[15 - i]);
    }

    float acc = 0.0f;
    if (qv) {
#pragma unroll
        for (int i = 0; i < 16; ++i)
            acc += sqrtf(fmaxf(s[i] + q2, 0.0f));   // true d2 = c + |q|^2
    }
#pragma unroll
    for (int off = 32; off > 0; off >>= 1) acc += __shfl_down(acc, off);
    const int lane = tid & 63, wid = tid >> 6;
    if (lane == 0) wsum[wid] = acc;
    __syncthreads();
    if (tid == 0)
        atomicAdd(out, (wsum[0] + wsum[1] + wsum[2] + wsum[3]) * scale_out);
}

extern "C" void kernel_launch(void* const* d_in, const int* in_sizes, int n_in,
                              void* d_out, int out_size, void* d_ws, size_t ws_size,
                              hipStream_t stream) {
    const float* src  = (const float*)d_in[0];   // pc_source [B,N,3]
    const float* tgt  = (const float*)d_in[1];   // pc_target [B,M,3]
    const float* flow = (const float*)d_in[2];   // pred_flow [B,N,3]
    float* out = (float*)d_out;

    const int B = 2;                              // per reference setup
    const int N = in_sizes[0] / (B * 3);
    const int M = in_sizes[1] / (B * 3);
    const int BN = B * N, BM = B * M;

    // workspace: pred4 | tgt4 | ps4 (guarded, sorted) | ts4 | goffs | minmax
    float4* pred4 = (float4*)d_ws;
    float4* tgt4  = pred4 + BN;
    float4* ps4   = tgt4 + BM;
    float4* ts4   = ps4 + (size_t)2 * (N + 2 * GUARD);
    int*    goffs = (int*)(ts4 + (size_t)2 * (M + 2 * GUARD));
    unsigned* mm  = (unsigned*)(goffs + 4 * (NB + 1));

    // out := 0 (replaces poisoned 0xAA); mm := 0xFF sentinels (both entries
    // are min-form in mapped space: mm[0]=min fmap(x), mm[1]=min fmap(-x)).
    hipMemsetAsync(out, 0, sizeof(float), stream);
    hipMemsetAsync(mm, 0xFF, 2 * sizeof(unsigned), stream);

    int maxBP = (BN > BM) ? BN : BM;
    pack_kernel<<<(maxBP + 255) / 256, 256, 0, stream>>>(
        src, tgt, flow, pred4, tgt4, mm, BN, BM);

    binsort_kernel<<<4, 1024, 0, stream>>>(pred4, tgt4, ps4, ts4, goffs, mm, N, M);

    int maxq = (N > M) ? N : M;
    dim3 grid((maxq + 15) / 16, 2 * B);   // 16 queries per 256-thr block
    float scale_out = 1.0f / (16.0f * 16.0f * (float)B * (float)N);
    scan_kernel<<<grid, 256, 0, stream>>>(ps4, ts4, goffs, mm, out, N, M, scale_out);
}